// Round 14
// baseline (104.041 us; speedup 1.0000x reference)
//
#include <hip/hip_runtime.h>
#include <hip/hip_bf16.h>
#include <stdint.h>

#define NN 8192
#define HH 256
#define GG 256

typedef __bf16 bf16x8 __attribute__((ext_vector_type(8)));
typedef float f32x4 __attribute__((ext_vector_type(4)));
typedef unsigned short u16v8 __attribute__((ext_vector_type(8)));

__device__ __forceinline__ ushort f2bf(float f) {
  union { float f; uint32_t u; } v; v.f = f;
  uint32_t u = v.u;
  u += 0x7fffu + ((u >> 16) & 1u);   // RNE
  return (ushort)(u >> 16);
}
__device__ __forceinline__ float bf2f(ushort h) {
  union { uint32_t u; float f; } v; v.u = ((uint32_t)h) << 16;
  return v.f;
}

// ---------------- prep: transpose p1w/p2w/aw -> bf16 [n][k]; convert r1w/r2w ----
__global__ __launch_bounds__(512) void k_prep(const float* __restrict__ p1w,
                                              const float* __restrict__ p2w,
                                              const float* __restrict__ aw,
                                              const float* __restrict__ r1w,
                                              const float* __restrict__ r2w,
                                              ushort* __restrict__ wT1,
                                              ushort* __restrict__ wT2,
                                              ushort* __restrict__ wTa,
                                              ushort* __restrict__ rK1,
                                              ushort* __restrict__ rK2) {
  int b = blockIdx.x, t = threadIdx.x;
  if (b < 48) {
    int mat = b >> 4, tile = b & 15;
    int tr = (tile >> 2) * 64, tc = (tile & 3) * 64;
    const float* w = mat == 0 ? p1w : mat == 1 ? p2w : aw;
    ushort* o = mat == 0 ? wT1 : mat == 1 ? wT2 : wTa;
    __shared__ float tileb[64][65];
    int rr = t >> 3, cg = (t & 7) * 8;
    const float* src = w + (size_t)(tr + rr) * HH + tc + cg;
    float4 v0 = *(const float4*)src;
    float4 v1 = *(const float4*)(src + 4);
    float* drow = &tileb[rr][cg];
    drow[0] = v0.x; drow[1] = v0.y; drow[2] = v0.z; drow[3] = v0.w;
    drow[4] = v1.x; drow[5] = v1.y; drow[6] = v1.z; drow[7] = v1.w;
    __syncthreads();
    int rn = t >> 3, kg = (t & 7) * 8;
    u16v8 a;
#pragma unroll
    for (int j = 0; j < 8; ++j) a[j] = f2bf(tileb[kg + j][rn]);
    *(u16v8*)(o + (size_t)(tc + rn) * HH + tr + kg) = a;
  } else {
    int eb = b - 48;
    const float* src = (eb < 8) ? r1w : r2w;
    ushort* dst = (eb < 8) ? rK1 : rK2;
    int sub = eb & 7;
#pragma unroll
    for (int it = 0; it < 2; ++it) {
      int base = sub * 8192 + it * 4096 + t * 8;
      float4 v0 = *(const float4*)(src + base);
      float4 v1 = *(const float4*)(src + base + 4);
      u16v8 o;
      o[0] = f2bf(v0.x); o[1] = f2bf(v0.y); o[2] = f2bf(v0.z); o[3] = f2bf(v0.w);
      o[4] = f2bf(v1.x); o[5] = f2bf(v1.y); o[6] = f2bf(v1.z); o[7] = f2bf(v1.w);
      *(u16v8*)(dst + base) = o;
    }
  }
}

// quarter loader: 32 KB, source chunk-swizzled (gload_lds writes linearly)
#define LOADQ(SRC, DST)                                                        \
  {                                                                            \
    _Pragma("unroll")                                                          \
    for (int it_ = 0; it_ < 2; ++it_) {                                        \
      int ch_ = it_ * 1024 + tid;                                              \
      int rw_ = ch_ >> 5, c_ = ch_ & 31;                                       \
      int sc_ = (ch_ & ~31) | (c_ ^ (rw_ & 7));                                \
      __builtin_amdgcn_global_load_lds(                                        \
          (const __attribute__((address_space(1))) uint32_t*)((SRC) + sc_ * 8),\
          (__attribute__((address_space(3))) uint32_t*)((DST) + ch_ * 8),      \
          16, 0, 0);                                                           \
    }                                                                          \
  }

// ---------------- main: one block per graph (R10 config, verbatim) ----------
__global__ __launch_bounds__(1024) void k_main(
    const float* __restrict__ x, const int* __restrict__ batch,
    const float* __restrict__ ab,
    const float* __restrict__ p1b, const float* __restrict__ p2b,
    const float* __restrict__ r1b, const float* __restrict__ r2b,
    const ushort* __restrict__ wT1, const ushort* __restrict__ wT2,
    const ushort* __restrict__ wTa,
    const ushort* __restrict__ rK1, const ushort* __restrict__ rK2,
    float* __restrict__ out) {
  __shared__ char smem[139808];
  ushort* wq0  = (ushort*)smem;               // 32 KB
  ushort* wq1  = (ushort*)(smem + 32768);     // 32 KB
  ushort* actA = (ushort*)(smem + 65536);     // 32 KB
  ushort* actB = (ushort*)(smem + 98304);     // 32 KB
  int*    bb   = (int*)(smem + 131072);       // 256 ints
  int*    mm   = (int*)(smem + 132096);       // 4 ints
  float*  colw = (float*)(smem + 132128);     // 256 f
  float*  xa   = (float*)(smem + 133152);     // 256 f
  float*  parts= (float*)(smem + 134176);     // 1024 f
  float*  pmax = (float*)(smem + 138272);     // 2*64 f
  float*  psum = (float*)(smem + 138784);     // 2*64 f
  float*  fct  = (float*)(smem + 139296);     // 2*64 f

  const int g = blockIdx.x, tid = threadIdx.x;
  const int lane = tid & 63, wid = tid >> 6;     // 16 waves
  const int l15 = lane & 15, q = lane >> 4, x7 = l15 & 7;

  // ---- row-range search ----
  if (tid < 256) bb[tid] = batch[tid * 32];
  if (tid == 0) { mm[0] = 256; mm[1] = 256; }
  __syncthreads();
  if (tid < 256) {
    int v = bb[tid];
    int pv = (tid == 0) ? -1 : bb[tid - 1];
    if (v >= g && pv < g) mm[0] = tid;
    if (v >= g + 1 && pv < g + 1) mm[1] = tid;
  }
  __syncthreads();
  {
    int which = -1, v = 0;
    if (tid < 32) { which = 2; v = g; }
    else if (tid >= 64 && tid < 96) { which = 3; v = g + 1; }
    if (which >= 0) {
      int B = mm[which - 2];
      int u = tid & 31;
      if (B == 0) { if (u == 0) mm[which] = 0; }
      else {
        int i = (B - 1) * 32 + 1 + u;
        if (i <= 8191 && batch[i] >= v && batch[i - 1] < v) mm[which] = i;
        if (B == 256 && u == 0 && batch[8191] < v) mm[which] = 8192;
      }
    }
  }
  __syncthreads();
  const int r0 = mm[2];
  int n = mm[3] - r0;
  if (n > 64) n = 64;
  const int nrt = (n + 15) >> 4;
  const int R = nrt * 16;

  // ---- prefetch stage 0 & 1 weights, overlapped with x staging ----
  LOADQ(wT1, wq0);
  LOADQ(wT1 + 16384, wq1);

  for (int ch = tid; ch < R * 32; ch += 1024) {
    int row = ch >> 5, c = ch & 31;
    int srow = r0 + row; if (srow > 8191) srow = 8191;
    const float* xp = x + (size_t)srow * HH + c * 8;
    float4 v0 = *(const float4*)xp;
    float4 v1 = *(const float4*)(xp + 4);
    u16v8 o;
    o[0] = f2bf(v0.x); o[1] = f2bf(v0.y); o[2] = f2bf(v0.z); o[3] = f2bf(v0.w);
    o[4] = f2bf(v1.x); o[5] = f2bf(v1.y); o[6] = f2bf(v1.z); o[7] = f2bf(v1.w);
    int dst = (ch & ~31) | (c ^ (row & 7));
    *(u16v8*)(actA + dst * 8) = o;
  }
  __syncthreads();

  // ---- phi: 12 pipelined stages (3 layers x 4 quarters of 64 cols) ----
  for (int s = 0; s < 12; ++s) {
    const int L = s >> 2, qd = s & 3;
    const ushort* cur = (s & 1) ? wq1 : wq0;
    if (s >= 1 && s < 11) {
      int sn = s + 1;
      int Ln = sn >> 2, qn = sn & 3;
      const ushort* wtn = (Ln == 0) ? wT1 : (Ln == 1) ? wT2 : wTa;
      ushort* dstb = (sn & 1) ? wq1 : wq0;
      LOADQ(wtn + qn * 16384, dstb);
    }
    const ushort* aIn = (L & 1) ? actB : actA;
    ushort* aOut = (L & 1) ? actA : actB;
    const float* bias = (L == 0) ? p1b : (L == 1) ? p2b : ab;
    const int dorelu = (L < 2);
    if (wid < nrt * 4) {
      int rt = wid >> 2, ct = wid & 3;
      f32x4 acc = {0.f, 0.f, 0.f, 0.f};
#pragma unroll
      for (int kk = 0; kk < 8; ++kk) {
        int kc = (kk * 4 + q) ^ x7;
        bf16x8 a  = *(const bf16x8*)(aIn + ((rt * 16 + l15) * 32 + kc) * 8);
        bf16x8 bf = *(const bf16x8*)(cur + ((ct * 16 + l15) * 32 + kc) * 8);
        acc = __builtin_amdgcn_mfma_f32_16x16x32_bf16(a, bf, acc, 0, 0, 0);
      }
      int col = qd * 64 + ct * 16 + l15;
      float bv = bias[col];
#pragma unroll
      for (int i = 0; i < 4; ++i) {
        float vv = acc[i] + bv;
        if (dorelu) vv = fmaxf(vv, 0.f);
        int r = rt * 16 + q * 4 + i;
        int cc = (col >> 3) ^ (r & 7);
        aOut[(r * 32 + cc) * 8 + (col & 7)] = f2bf(vv);
      }
    }
    __syncthreads();
  }
  // h = actA, s = actB (swizzled [64][256] bf16)

  // ---- attention: Gram(s) over 8 waves (4 row-tiles x 2 col-halves) ----
  if (tid < 256) colw[tid] = 0.f;
  __syncthreads();
  const int rt = wid & 3, h2 = wid >> 2;
  const bool liveW = (wid < 8) && (rt * 16 < n);
  float e0[4], e1[4];
  int cb0 = 0, cb1 = 0;
  if (liveW) {
    const char* stc = (const char*)actB;
    cb0 = (h2 * 2 + 0) * 16; cb1 = (h2 * 2 + 1) * 16;
    f32x4 acc0 = {0.f, 0.f, 0.f, 0.f}, acc1 = acc0;
    const int arow = rt * 16 + l15;
    if (cb0 < n) {
#pragma unroll
      for (int kk = 0; kk < 8; kk++) {
        int kc = ((kk * 4 + q) ^ x7) << 4;
        bf16x8 a  = *(const bf16x8*)(stc + arow * 512 + kc);
        bf16x8 b0 = *(const bf16x8*)(stc + (cb0 + l15) * 512 + kc);
        acc0 = __builtin_amdgcn_mfma_f32_16x16x32_bf16(a, b0, acc0, 0, 0, 0);
        if (cb1 < n) {
          bf16x8 b1 = *(const bf16x8*)(stc + (cb1 + l15) * 512 + kc);
          acc1 = __builtin_amdgcn_mfma_f32_16x16x32_bf16(a, b1, acc1, 0, 0, 0);
        }
      }
    }
    float pm[4], ps[4];
#pragma unroll
    for (int i = 0; i < 4; i++) {
      float mmx = (cb0 + l15 < n) ? acc0[i] : -1e30f;
      if (cb1 + l15 < n) mmx = fmaxf(mmx, acc1[i]);
      pm[i] = mmx;
    }
#pragma unroll
    for (int off = 1; off < 16; off <<= 1)
#pragma unroll
      for (int i = 0; i < 4; i++) pm[i] = fmaxf(pm[i], __shfl_xor(pm[i], off));
#pragma unroll
    for (int i = 0; i < 4; i++) {
      e0[i] = (cb0 + l15 < n) ? __expf(acc0[i] - pm[i]) : 0.f;
      e1[i] = (cb1 + l15 < n) ? __expf(acc1[i] - pm[i]) : 0.f;
      ps[i] = e0[i] + e1[i];
    }
#pragma unroll
    for (int off = 1; off < 16; off <<= 1)
#pragma unroll
      for (int i = 0; i < 4; i++) ps[i] += __shfl_xor(ps[i], off);
    if (l15 == 0) {
#pragma unroll
      for (int i = 0; i < 4; i++) {
        int row = rt * 16 + q * 4 + i;
        pmax[h2 * 64 + row] = pm[i];
        psum[h2 * 64 + row] = ps[i];
      }
    }
  }
  __syncthreads();
  if (tid < 128) {
    int h = tid >> 6, row = tid & 63;
    float m0 = pmax[row], m1 = pmax[64 + row];
    float m = fmaxf(m0, m1);
    float S = psum[row] * __expf(m0 - m) + psum[64 + row] * __expf(m1 - m);
    fct[h * 64 + row] = (S > 0.f) ? __expf(pmax[h * 64 + row] - m) / S : 0.f;
  }
  __syncthreads();
  if (liveW) {
    float cs0 = 0.f, cs1 = 0.f;
#pragma unroll
    for (int i = 0; i < 4; i++) {
      int row = rt * 16 + q * 4 + i;
      if (row < n) {
        float f = fct[h2 * 64 + row];
        cs0 += e0[i] * f;
        cs1 += e1[i] * f;
      }
    }
    cs0 += __shfl_xor(cs0, 16); cs0 += __shfl_xor(cs0, 32);
    cs1 += __shfl_xor(cs1, 16); cs1 += __shfl_xor(cs1, 32);
    if (lane < 16) {
      if (cb0 < n) atomicAdd(&colw[cb0 + l15], cs0);
      if (cb1 < n) atomicAdd(&colw[cb1 + l15], cs1);
    }
  }
  __syncthreads();

  // ---- aggregation: xa[c] = sum_j colw[j] * h[j][c], 4-way split ----
  {
    int c = tid & 255, qr = tid >> 8;
    float agg = 0.f;
    for (int jj = qr; jj < n; jj += 4) {
      int cc = (c >> 3) ^ (jj & 7);
      agg = fmaf(colw[jj], bf2f(actA[(jj * 32 + cc) * 8 + (c & 7)]), agg);
    }
    parts[qr * 256 + c] = agg;
  }
  __syncthreads();
  if (tid < 256)
    xa[tid] = (parts[tid] + parts[256 + tid]) + (parts[512 + tid] + parts[768 + tid]);
  __syncthreads();

  // ---- rho GEMV: out[g] = relu(relu(xa@r1w+b1)@r2w+b2), 4-way k split ----
  {
    const int col = tid & 255, kq = tid >> 8;
    const int k0 = kq * 64;
    float a0 = 0.f, a1 = 0.f, a2 = 0.f, a3 = 0.f;
    const ushort* wp = rK1 + (size_t)k0 * HH + col;
#pragma unroll 4
    for (int k = 0; k < 64; k += 4) {
      a0 = fmaf(xa[k0 + k],     bf2f(wp[(size_t)(k)     * HH]), a0);
      a1 = fmaf(xa[k0 + k + 1], bf2f(wp[(size_t)(k + 1) * HH]), a1);
      a2 = fmaf(xa[k0 + k + 2], bf2f(wp[(size_t)(k + 2) * HH]), a2);
      a3 = fmaf(xa[k0 + k + 3], bf2f(wp[(size_t)(k + 3) * HH]), a3);
    }
    parts[kq * 256 + col] = (a0 + a1) + (a2 + a3);
    __syncthreads();
    if (tid < 256)
      colw[tid] = fmaxf(r1b[tid] + (parts[tid] + parts[256 + tid]) +
                        (parts[512 + tid] + parts[768 + tid]), 0.f);
    __syncthreads();
    a0 = a1 = a2 = a3 = 0.f;
    const ushort* wp2 = rK2 + (size_t)k0 * HH + col;
#pragma unroll 4
    for (int k = 0; k < 64; k += 4) {
      a0 = fmaf(colw[k0 + k],     bf2f(wp2[(size_t)(k)     * HH]), a0);
      a1 = fmaf(colw[k0 + k + 1], bf2f(wp2[(size_t)(k + 1) * HH]), a1);
      a2 = fmaf(colw[k0 + k + 2], bf2f(wp2[(size_t)(k + 2) * HH]), a2);
      a3 = fmaf(colw[k0 + k + 3], bf2f(wp2[(size_t)(k + 3) * HH]), a3);
    }
    parts[kq * 256 + col] = (a0 + a1) + (a2 + a3);
    __syncthreads();
    if (tid < 256)
      out[(size_t)g * HH + tid] = fmaxf(r2b[tid] + (parts[tid] + parts[256 + tid]) +
                                        (parts[512 + tid] + parts[768 + tid]), 0.f);
  }
}

// ---------------- launcher (DIAGNOSTIC: k_main x4, idempotent) --------------
extern "C" void kernel_launch(void* const* d_in, const int* in_sizes, int n_in,
                              void* d_out, int out_size, void* d_ws, size_t ws_size,
                              hipStream_t stream) {
  const float* x   = (const float*)d_in[0];
  const int* batch = (const int*)d_in[1];
  const float* aw  = (const float*)d_in[3];
  const float* ab  = (const float*)d_in[4];
  const float* p1w = (const float*)d_in[5];
  const float* p1b = (const float*)d_in[6];
  const float* p2w = (const float*)d_in[7];
  const float* p2b = (const float*)d_in[8];
  const float* r1w = (const float*)d_in[9];
  const float* r1b = (const float*)d_in[10];
  const float* r2w = (const float*)d_in[11];
  const float* r2b = (const float*)d_in[12];
  float* out = (float*)d_out;

  char* ws = (char*)d_ws;
  ushort* wT1 = (ushort*)(ws);            // 128 KB each
  ushort* wT2 = wT1 + 65536;
  ushort* wTa = wT2 + 65536;
  ushort* rK1 = wTa + 65536;
  ushort* rK2 = rK1 + 65536;

  k_prep<<<dim3(64), dim3(512), 0, stream>>>(p1w, p2w, aw, r1w, r2w,
                                             wT1, wT2, wTa, rK1, rK2);
  // Diagnostic: 4 identical, idempotent k_main dispatches. dur_us slope vs
  // R10's single-dispatch 33.3 gives k_main's true per-dispatch cost.
  for (int rep = 0; rep < 4; ++rep)
    k_main<<<dim3(256), dim3(1024), 0, stream>>>(x, batch, ab, p1b, p2b, r1b, r2b,
                                                 wT1, wT2, wTa, rK1, rK2, out);
}

// Round 15
// 34.006 us; speedup vs baseline: 3.0595x; 3.0595x over previous
//
#include <hip/hip_runtime.h>
#include <hip/hip_bf16.h>
#include <stdint.h>

#define NN 8192
#define HH 256
#define GG 256

typedef __bf16 bf16x8 __attribute__((ext_vector_type(8)));
typedef float f32x4 __attribute__((ext_vector_type(4)));
typedef unsigned short u16v8 __attribute__((ext_vector_type(8)));

__device__ __forceinline__ ushort f2bf(float f) {
  union { float f; uint32_t u; } v; v.f = f;
  uint32_t u = v.u;
  u += 0x7fffu + ((u >> 16) & 1u);   // RNE
  return (ushort)(u >> 16);
}
__device__ __forceinline__ float bf2f(ushort h) {
  union { uint32_t u; float f; } v; v.u = ((uint32_t)h) << 16;
  return v.f;
}

// ---------------- prep: transpose p1w/p2w/aw -> bf16 [n][k]; convert r1w/r2w ----
__global__ __launch_bounds__(512) void k_prep(const float* __restrict__ p1w,
                                              const float* __restrict__ p2w,
                                              const float* __restrict__ aw,
                                              const float* __restrict__ r1w,
                                              const float* __restrict__ r2w,
                                              ushort* __restrict__ wT1,
                                              ushort* __restrict__ wT2,
                                              ushort* __restrict__ wTa,
                                              ushort* __restrict__ rK1,
                                              ushort* __restrict__ rK2) {
  int b = blockIdx.x, t = threadIdx.x;
  if (b < 48) {
    int mat = b >> 4, tile = b & 15;
    int tr = (tile >> 2) * 64, tc = (tile & 3) * 64;
    const float* w = mat == 0 ? p1w : mat == 1 ? p2w : aw;
    ushort* o = mat == 0 ? wT1 : mat == 1 ? wT2 : wTa;
    __shared__ float tileb[64][65];
    int rr = t >> 3, cg = (t & 7) * 8;
    const float* src = w + (size_t)(tr + rr) * HH + tc + cg;
    float4 v0 = *(const float4*)src;
    float4 v1 = *(const float4*)(src + 4);
    float* drow = &tileb[rr][cg];
    drow[0] = v0.x; drow[1] = v0.y; drow[2] = v0.z; drow[3] = v0.w;
    drow[4] = v1.x; drow[5] = v1.y; drow[6] = v1.z; drow[7] = v1.w;
    __syncthreads();
    int rn = t >> 3, kg = (t & 7) * 8;
    u16v8 a;
#pragma unroll
    for (int j = 0; j < 8; ++j) a[j] = f2bf(tileb[kg + j][rn]);
    *(u16v8*)(o + (size_t)(tc + rn) * HH + tr + kg) = a;
  } else {
    int eb = b - 48;
    const float* src = (eb < 8) ? r1w : r2w;
    ushort* dst = (eb < 8) ? rK1 : rK2;
    int sub = eb & 7;
#pragma unroll
    for (int it = 0; it < 2; ++it) {
      int base = sub * 8192 + it * 4096 + t * 8;
      float4 v0 = *(const float4*)(src + base);
      float4 v1 = *(const float4*)(src + base + 4);
      u16v8 o;
      o[0] = f2bf(v0.x); o[1] = f2bf(v0.y); o[2] = f2bf(v0.z); o[3] = f2bf(v0.w);
      o[4] = f2bf(v1.x); o[5] = f2bf(v1.y); o[6] = f2bf(v1.z); o[7] = f2bf(v1.w);
      *(u16v8*)(dst + base) = o;
    }
  }
}

// ---------------- main: one block per graph, phi weights in REGISTERS -------
__global__ __launch_bounds__(1024) void k_main(
    const float* __restrict__ x, const int* __restrict__ batch,
    const float* __restrict__ ab,
    const float* __restrict__ p1b, const float* __restrict__ p2b,
    const float* __restrict__ r1b, const float* __restrict__ r2b,
    const ushort* __restrict__ wT1, const ushort* __restrict__ wT2,
    const ushort* __restrict__ wTa,
    const ushort* __restrict__ rK1, const ushort* __restrict__ rK2,
    float* __restrict__ out) {
  __shared__ ushort actA[16384];   // 32 KB, chunk-swizzled c^(r&7)
  __shared__ ushort actB[16384];   // 32 KB
  __shared__ int bb[256];
  __shared__ int mm[4];
  __shared__ float colw[256];
  __shared__ float xa[256];
  __shared__ float parts[1024];
  __shared__ float pmax[128];
  __shared__ float psum[128];
  __shared__ float fct[128];

  const int g = blockIdx.x, tid = threadIdx.x;
  const int lane = tid & 63, wid = tid >> 6;     // 16 waves
  const int l15 = lane & 15, q = lane >> 4, x7 = l15 & 7;

  // ---- row-range search: 2-round parallel lower_bound for g and g+1 ----
  if (tid < 256) bb[tid] = batch[tid * 32];
  if (tid == 0) { mm[0] = 256; mm[1] = 256; }
  __syncthreads();
  if (tid < 256) {
    int v = bb[tid];
    int pv = (tid == 0) ? -1 : bb[tid - 1];
    if (v >= g && pv < g) mm[0] = tid;
    if (v >= g + 1 && pv < g + 1) mm[1] = tid;
  }
  __syncthreads();
  {
    int which = -1, v = 0;
    if (tid < 32) { which = 2; v = g; }
    else if (tid >= 64 && tid < 96) { which = 3; v = g + 1; }
    if (which >= 0) {
      int B = mm[which - 2];
      int u = tid & 31;
      if (B == 0) { if (u == 0) mm[which] = 0; }
      else {
        int i = (B - 1) * 32 + 1 + u;
        if (i <= 8191 && batch[i] >= v && batch[i - 1] < v) mm[which] = i;
        if (B == 256 && u == 0 && batch[8191] < v) mm[which] = 8192;
      }
    }
  }
  __syncthreads();
  const int r0 = mm[2];
  int n = mm[3] - r0;
  if (n > 64) n = 64;
  const int R = ((n + 15) >> 4) * 16;

  // ---- stage x rows -> actA (bf16, swizzled) ----
  for (int ch = tid; ch < R * 32; ch += 1024) {
    int row = ch >> 5, c = ch & 31;
    int srow = r0 + row; if (srow > 8191) srow = 8191;
    const float* xp = x + (size_t)srow * HH + c * 8;
    float4 v0 = *(const float4*)xp;
    float4 v1 = *(const float4*)(xp + 4);
    u16v8 o;
    o[0] = f2bf(v0.x); o[1] = f2bf(v0.y); o[2] = f2bf(v0.z); o[3] = f2bf(v0.w);
    o[4] = f2bf(v1.x); o[5] = f2bf(v1.y); o[6] = f2bf(v1.z); o[7] = f2bf(v1.w);
    int dst = (ch & ~31) | (c ^ (row & 7));
    *(u16v8*)(actA + dst * 8) = o;
  }
  __syncthreads();

  // ---- phi: 3 layers, weights held in registers (wave owns 16 cols) -------
  // B-frag layout (verified R1): lane(q,l15): col = wid*16+l15,
  // k = kk*32 + q*8 .. +7  ->  wT[(col)*256 + kk*32 + q*8], 16B, line-coalesced.
  const int mycol = wid * 16 + l15;
  const ushort* wrow1 = wT1 + (size_t)mycol * HH + q * 8;
  const ushort* wrow2 = wT2 + (size_t)mycol * HH + q * 8;
  const ushort* wrowa = wTa + (size_t)mycol * HH + q * 8;
  bf16x8 wA[8], wB[8];
#pragma unroll
  for (int kk = 0; kk < 8; ++kk) wA[kk] = *(const bf16x8*)(wrow1 + kk * 32);
#pragma unroll
  for (int kk = 0; kk < 8; ++kk) wB[kk] = *(const bf16x8*)(wrow2 + kk * 32);

  // ---- Layer 0: actA -> actB (relu) ----
  {
    float bv = p1b[mycol];
#pragma unroll
    for (int rt4 = 0; rt4 < 4; ++rt4) {
      if (rt4 * 16 < n) {
        f32x4 acc = {0.f, 0.f, 0.f, 0.f};
#pragma unroll
        for (int kk = 0; kk < 8; ++kk) {
          int ca = (kk * 4 + q) ^ x7;
          bf16x8 a = *(const bf16x8*)(actA + ((rt4 * 16 + l15) * 32 + ca) * 8);
          acc = __builtin_amdgcn_mfma_f32_16x16x32_bf16(a, wA[kk], acc, 0, 0, 0);
        }
#pragma unroll
        for (int i = 0; i < 4; ++i) {
          float vv = fmaxf(acc[i] + bv, 0.f);
          int r = rt4 * 16 + q * 4 + i;
          int cc = (mycol >> 3) ^ (r & 7);
          actB[(r * 32 + cc) * 8 + (mycol & 7)] = f2bf(vv);
        }
      }
    }
  }
  __syncthreads();
  // reload wA <- wTa for layer 2 (latency hidden under L1 compute)
#pragma unroll
  for (int kk = 0; kk < 8; ++kk) wA[kk] = *(const bf16x8*)(wrowa + kk * 32);

  // ---- Layer 1: actB -> actA = h (relu) ----
  {
    float bv = p2b[mycol];
#pragma unroll
    for (int rt4 = 0; rt4 < 4; ++rt4) {
      if (rt4 * 16 < n) {
        f32x4 acc = {0.f, 0.f, 0.f, 0.f};
#pragma unroll
        for (int kk = 0; kk < 8; ++kk) {
          int ca = (kk * 4 + q) ^ x7;
          bf16x8 a = *(const bf16x8*)(actB + ((rt4 * 16 + l15) * 32 + ca) * 8);
          acc = __builtin_amdgcn_mfma_f32_16x16x32_bf16(a, wB[kk], acc, 0, 0, 0);
        }
#pragma unroll
        for (int i = 0; i < 4; ++i) {
          float vv = fmaxf(acc[i] + bv, 0.f);
          int r = rt4 * 16 + q * 4 + i;
          int cc = (mycol >> 3) ^ (r & 7);
          actA[(r * 32 + cc) * 8 + (mycol & 7)] = f2bf(vv);
        }
      }
    }
  }
  __syncthreads();

  // ---- Layer 2: actA -> actB = s (no relu) ----
  {
    float bv = ab[mycol];
#pragma unroll
    for (int rt4 = 0; rt4 < 4; ++rt4) {
      if (rt4 * 16 < n) {
        f32x4 acc = {0.f, 0.f, 0.f, 0.f};
#pragma unroll
        for (int kk = 0; kk < 8; ++kk) {
          int ca = (kk * 4 + q) ^ x7;
          bf16x8 a = *(const bf16x8*)(actA + ((rt4 * 16 + l15) * 32 + ca) * 8);
          acc = __builtin_amdgcn_mfma_f32_16x16x32_bf16(a, wA[kk], acc, 0, 0, 0);
        }
#pragma unroll
        for (int i = 0; i < 4; ++i) {
          float vv = acc[i] + bv;
          int r = rt4 * 16 + q * 4 + i;
          int cc = (mycol >> 3) ^ (r & 7);
          actB[(r * 32 + cc) * 8 + (mycol & 7)] = f2bf(vv);
        }
      }
    }
  }
  __syncthreads();
  // h = actA, s = actB (swizzled [64][256] bf16)

  // ---- attention: Gram(s) over 8 waves (4 row-tiles x 2 col-halves) ----
  if (tid < 256) colw[tid] = 0.f;
  __syncthreads();
  const int rt = wid & 3, h2 = wid >> 2;
  const bool liveW = (wid < 8) && (rt * 16 < n);
  float e0[4], e1[4];
  int cb0 = 0, cb1 = 0;
  if (liveW) {
    const char* stc = (const char*)actB;
    cb0 = (h2 * 2 + 0) * 16; cb1 = (h2 * 2 + 1) * 16;
    f32x4 acc0 = {0.f, 0.f, 0.f, 0.f}, acc1 = acc0;
    const int arow = rt * 16 + l15;
    if (cb0 < n) {
#pragma unroll
      for (int kk = 0; kk < 8; kk++) {
        int kc = ((kk * 4 + q) ^ x7) << 4;
        bf16x8 a  = *(const bf16x8*)(stc + arow * 512 + kc);
        bf16x8 b0 = *(const bf16x8*)(stc + (cb0 + l15) * 512 + kc);
        acc0 = __builtin_amdgcn_mfma_f32_16x16x32_bf16(a, b0, acc0, 0, 0, 0);
        if (cb1 < n) {
          bf16x8 b1 = *(const bf16x8*)(stc + (cb1 + l15) * 512 + kc);
          acc1 = __builtin_amdgcn_mfma_f32_16x16x32_bf16(a, b1, acc1, 0, 0, 0);
        }
      }
    }
    float pm[4], ps[4];
#pragma unroll
    for (int i = 0; i < 4; i++) {
      float mmx = (cb0 + l15 < n) ? acc0[i] : -1e30f;
      if (cb1 + l15 < n) mmx = fmaxf(mmx, acc1[i]);
      pm[i] = mmx;
    }
#pragma unroll
    for (int off = 1; off < 16; off <<= 1)
#pragma unroll
      for (int i = 0; i < 4; i++) pm[i] = fmaxf(pm[i], __shfl_xor(pm[i], off));
#pragma unroll
    for (int i = 0; i < 4; i++) {
      e0[i] = (cb0 + l15 < n) ? __expf(acc0[i] - pm[i]) : 0.f;
      e1[i] = (cb1 + l15 < n) ? __expf(acc1[i] - pm[i]) : 0.f;
      ps[i] = e0[i] + e1[i];
    }
#pragma unroll
    for (int off = 1; off < 16; off <<= 1)
#pragma unroll
      for (int i = 0; i < 4; i++) ps[i] += __shfl_xor(ps[i], off);
    if (l15 == 0) {
#pragma unroll
      for (int i = 0; i < 4; i++) {
        int row = rt * 16 + q * 4 + i;
        pmax[h2 * 64 + row] = pm[i];
        psum[h2 * 64 + row] = ps[i];
      }
    }
  }
  __syncthreads();
  if (tid < 128) {
    int h = tid >> 6, row = tid & 63;
    float m0 = pmax[row], m1 = pmax[64 + row];
    float m = fmaxf(m0, m1);
    float S = psum[row] * __expf(m0 - m) + psum[64 + row] * __expf(m1 - m);
    fct[h * 64 + row] = (S > 0.f) ? __expf(pmax[h * 64 + row] - m) / S : 0.f;
  }
  __syncthreads();
  if (liveW) {
    float cs0 = 0.f, cs1 = 0.f;
#pragma unroll
    for (int i = 0; i < 4; i++) {
      int row = rt * 16 + q * 4 + i;
      if (row < n) {
        float f = fct[h2 * 64 + row];
        cs0 += e0[i] * f;
        cs1 += e1[i] * f;
      }
    }
    cs0 += __shfl_xor(cs0, 16); cs0 += __shfl_xor(cs0, 32);
    cs1 += __shfl_xor(cs1, 16); cs1 += __shfl_xor(cs1, 32);
    if (lane < 16) {
      if (cb0 < n) atomicAdd(&colw[cb0 + l15], cs0);
      if (cb1 < n) atomicAdd(&colw[cb1 + l15], cs1);
    }
  }
  __syncthreads();

  // ---- aggregation: xa[c] = sum_j colw[j] * h[j][c], 4-way split ----
  {
    int c = tid & 255, qr = tid >> 8;
    float agg = 0.f;
    for (int jj = qr; jj < n; jj += 4) {
      int cc = (c >> 3) ^ (jj & 7);
      agg = fmaf(colw[jj], bf2f(actA[(jj * 32 + cc) * 8 + (c & 7)]), agg);
    }
    parts[qr * 256 + c] = agg;
  }
  __syncthreads();
  if (tid < 256)
    xa[tid] = (parts[tid] + parts[256 + tid]) + (parts[512 + tid] + parts[768 + tid]);
  __syncthreads();

  // ---- rho GEMV: out[g] = relu(relu(xa@r1w+b1)@r2w+b2), 4-way k split ----
  {
    const int col = tid & 255, kq = tid >> 8;
    const int k0 = kq * 64;
    float a0 = 0.f, a1 = 0.f, a2 = 0.f, a3 = 0.f;
    const ushort* wp = rK1 + (size_t)k0 * HH + col;
#pragma unroll 4
    for (int k = 0; k < 64; k += 4) {
      a0 = fmaf(xa[k0 + k],     bf2f(wp[(size_t)(k)     * HH]), a0);
      a1 = fmaf(xa[k0 + k + 1], bf2f(wp[(size_t)(k + 1) * HH]), a1);
      a2 = fmaf(xa[k0 + k + 2], bf2f(wp[(size_t)(k + 2) * HH]), a2);
      a3 = fmaf(xa[k0 + k + 3], bf2f(wp[(size_t)(k + 3) * HH]), a3);
    }
    parts[kq * 256 + col] = (a0 + a1) + (a2 + a3);
    __syncthreads();
    if (tid < 256)
      colw[tid] = fmaxf(r1b[tid] + (parts[tid] + parts[256 + tid]) +
                        (parts[512 + tid] + parts[768 + tid]), 0.f);
    __syncthreads();
    a0 = a1 = a2 = a3 = 0.f;
    const ushort* wp2 = rK2 + (size_t)k0 * HH + col;
#pragma unroll 4
    for (int k = 0; k < 64; k += 4) {
      a0 = fmaf(colw[k0 + k],     bf2f(wp2[(size_t)(k)     * HH]), a0);
      a1 = fmaf(colw[k0 + k + 1], bf2f(wp2[(size_t)(k + 1) * HH]), a1);
      a2 = fmaf(colw[k0 + k + 2], bf2f(wp2[(size_t)(k + 2) * HH]), a2);
      a3 = fmaf(colw[k0 + k + 3], bf2f(wp2[(size_t)(k + 3) * HH]), a3);
    }
    parts[kq * 256 + col] = (a0 + a1) + (a2 + a3);
    __syncthreads();
    if (tid < 256)
      out[(size_t)g * HH + tid] = fmaxf(r2b[tid] + (parts[tid] + parts[256 + tid]) +
                                        (parts[512 + tid] + parts[768 + tid]), 0.f);
  }
}

// ---------------- launcher ----------------
extern "C" void kernel_launch(void* const* d_in, const int* in_sizes, int n_in,
                              void* d_out, int out_size, void* d_ws, size_t ws_size,
                              hipStream_t stream) {
  const float* x   = (const float*)d_in[0];
  const int* batch = (const int*)d_in[1];
  const float* aw  = (const float*)d_in[3];
  const float* ab  = (const float*)d_in[4];
  const float* p1w = (const float*)d_in[5];
  const float* p1b = (const float*)d_in[6];
  const float* p2w = (const float*)d_in[7];
  const float* p2b = (const float*)d_in[8];
  const float* r1w = (const float*)d_in[9];
  const float* r1b = (const float*)d_in[10];
  const float* r2w = (const float*)d_in[11];
  const float* r2b = (const float*)d_in[12];
  float* out = (float*)d_out;

  char* ws = (char*)d_ws;
  ushort* wT1 = (ushort*)(ws);            // 128 KB each
  ushort* wT2 = wT1 + 65536;
  ushort* wTa = wT2 + 65536;
  ushort* rK1 = wTa + 65536;
  ushort* rK2 = rK1 + 65536;

  k_prep<<<dim3(64), dim3(512), 0, stream>>>(p1w, p2w, aw, r1w, r2w,
                                             wT1, wT2, wTa, rK1, rK2);
  k_main<<<dim3(256), dim3(1024), 0, stream>>>(x, batch, ab, p1b, p2b, r1b, r2b,
                                               wT1, wT2, wTa, rK1, rK2, out);
}